// Round 12
// baseline (242.521 us; speedup 1.0000x reference)
//
#include <hip/hip_runtime.h>
#include <cstdint>
#include <cstddef>

#define NPTS   4096
#define BATCH  4
#define KNN    8
#define NC     8           // chunks per cloud scan
#define CHN    (NPTS / NC) // 512 candidates per chunk
#define GRID   1024        // 2 clouds * 4 batch * 16 igroups * 8 chunks
#define NMERGE 256         // last finishers run phase-2 (64 points, 4 lanes each)
#define EPS_F  1e-12f

__device__ __forceinline__ uint32_t u32min(uint32_t a, uint32_t b) { return a < b ? a : b; }
__device__ __forceinline__ uint32_t u32max(uint32_t a, uint32_t b) { return a > b ? a : b; }

// v_med3_u32: for sorted a<=b, med3(a,b,x) == clamp(x,a,b) — one instruction.
__device__ __forceinline__ uint32_t umed3(uint32_t a, uint32_t b, uint32_t c) {
  uint32_t d;
  asm("v_med3_u32 %0, %1, %2, %3" : "=v"(d) : "v"(a), "v"(b), "v"(c));
  return d;
}

// Insert key into ascending D-list, dropping the largest: 1 min + (D-1) med3.
template <int D>
__device__ __forceinline__ void insertD(uint32_t (&loc)[D], uint32_t key) {
  uint32_t prev = loc[0];
  loc[0] = u32min(prev, key);
#pragma unroll
  for (int m = 1; m < D; ++m) {
    const uint32_t cur = loc[m];
    loc[m] = umed3(prev, cur, key);
    prev = cur;
  }
}

// Proven float4 candidate-stream scan (R4 structure), depth-parametric:
// D=8 for non-self chunks (top-8 directly), D=9 for the self chunk
// (self d2 == +0 exactly -> rank-0; caller drops it).
template <int D>
__device__ __forceinline__ void scan_chunk(const float4* __restrict__ c4, int j0,
                                           float xix, float xiy, float xiz,
                                           uint32_t (&loc)[D]) {
#pragma unroll
  for (int k = 0; k < D; ++k) loc[k] = 0xFFFFFFFFu;
#pragma unroll 4
  for (int t4 = 0; t4 < CHN / 4; ++t4) {
    const float4 q0 = c4[3 * t4 + 0];  // x0 y0 z0 x1
    const float4 q1 = c4[3 * t4 + 1];  // y1 z1 x2 y2
    const float4 q2 = c4[3 * t4 + 2];  // z2 x3 y3 z3
    const uint32_t jb = (uint32_t)(j0 + 4 * t4);
    {
      const float dx = xix - q0.x, dy = xiy - q0.y, dz = xiz - q0.z;
      const float d2 = fmaf(dx, dx, fmaf(dy, dy, dz * dz));
      insertD<D>(loc, (__float_as_uint(d2) & 0xFFFFF000u) | (jb + 0u));
    }
    {
      const float dx = xix - q0.w, dy = xiy - q1.x, dz = xiz - q1.y;
      const float d2 = fmaf(dx, dx, fmaf(dy, dy, dz * dz));
      insertD<D>(loc, (__float_as_uint(d2) & 0xFFFFF000u) | (jb + 1u));
    }
    {
      const float dx = xix - q1.z, dy = xiy - q1.w, dz = xiz - q2.x;
      const float d2 = fmaf(dx, dx, fmaf(dy, dy, dz * dz));
      insertD<D>(loc, (__float_as_uint(d2) & 0xFFFFF000u) | (jb + 2u));
    }
    {
      const float dx = xix - q2.y, dy = xiy - q2.z, dz = xiz - q2.w;
      const float d2 = fmaf(dx, dx, fmaf(dy, dy, dz * dz));
      insertD<D>(loc, (__float_as_uint(d2) & 0xFFFFF000u) | (jb + 3u));
    }
  }
}

// Merge two sorted-ascending 8-lists, keep the smallest 8, sorted (20 ops).
__device__ __forceinline__ void merge2(uint32_t A[KNN], const uint32_t B[KNN]) {
  uint32_t t[KNN];
#pragma unroll
  for (int m = 0; m < KNN; ++m) t[m] = u32min(A[m], B[KNN - 1 - m]);
#define CEU(x, y) { uint32_t lo = u32min(t[x], t[y]); uint32_t hi = u32max(t[x], t[y]); t[x] = lo; t[y] = hi; }
  CEU(0,4) CEU(1,5) CEU(2,6) CEU(3,7)
  CEU(0,2) CEU(1,3) CEU(4,6) CEU(5,7)
  CEU(0,1) CEU(2,3) CEU(4,5) CEU(6,7)
#undef CEU
#pragma unroll
  for (int m = 0; m < KNN; ++m) A[m] = t[m];
}

// ---------------------------------------------------------------------------
// ONE kernel. Phase 1: proven scan (NC=8, 1024 blocks = 4/CU), depth-split
// insert8/insert9 on the block-uniform self-chunk predicate. Ticket ranks
// completion; last NMERGE=256 blocks spin (ticket-then-spin => deadlock-free
// at any occupancy), then run the R11 4-lane loss body for 64 points each.
// KEY FIX vs R10: phase-2 uses the low-pressure 4-lane merge (H=4 lists =
// 32-reg staging, ~60 live max) so the compiler cannot spill phase-2 to
// scratch — R10's VGPR-52 + 22% occupancy signature was scratch reservation
// capping resident waves and exposing phase-1 to memory latency.
// ---------------------------------------------------------------------------
__global__ void __launch_bounds__(256, 4)
fused_k(const float* __restrict__ pred, const float* __restrict__ tgt,
        uint32_t* __restrict__ partial, double* __restrict__ acc,
        uint32_t* __restrict__ counters, float* __restrict__ out) {
  const int tid = threadIdx.x;
  __shared__ unsigned sbc[2];
  __shared__ float red[12];

  // ---------------- phase 1 ----------------
  {
    int bx = blockIdx.x;
    const int chunk = bx & (NC - 1); bx /= NC;
    const int ig    = bx & 15; bx >>= 4;
    const int b     = bx & 3;  bx >>= 2;
    const int cloud = bx;  // 0 = pred, 1 = target

    const float* __restrict__ pts = (cloud ? tgt : pred) + (size_t)b * NPTS * 3;
    const int i = ig * 256 + tid;
    const int j0 = chunk * CHN;
    const float xix = pts[3 * i], xiy = pts[3 * i + 1], xiz = pts[3 * i + 2];
    const float4* __restrict__ c4 = (const float4*)(pts + 3 * j0);

    uint4 o0, o1;
    if (((ig * 256) / CHN) == chunk) {          // self chunk (block-uniform)
      uint32_t loc[KNN + 1];
      scan_chunk<KNN + 1>(c4, j0, xix, xiy, xiz, loc);
      o0 = make_uint4(loc[1], loc[2], loc[3], loc[4]);
      o1 = make_uint4(loc[5], loc[6], loc[7], loc[8]);
    } else {
      uint32_t loc[KNN];
      scan_chunk<KNN>(c4, j0, xix, xiy, xiz, loc);
      o0 = make_uint4(loc[0], loc[1], loc[2], loc[3]);
      o1 = make_uint4(loc[4], loc[5], loc[6], loc[7]);
    }
    uint32_t* pw = partial +
        ((((size_t)(cloud * BATCH + b) * NC + chunk) * NPTS) + (size_t)i) * KNN;
    *(uint4*)pw = o0;
    *(uint4*)(pw + 4) = o1;
  }

  // ---------------- ticket (ticket first, then spin: deadlock-free) -------
  __threadfence();            // release partials
  __syncthreads();
  if (tid == 0) sbc[0] = atomicAdd(&counters[0], 1u) + 1u;
  __syncthreads();
  const unsigned rank = sbc[0];
  if (rank <= (unsigned)(GRID - NMERGE)) return;
  const int slice = (int)(rank - (GRID - NMERGE) - 1);  // 0..255

  if (tid == 0) {
    while (__hip_atomic_load(&counters[0], __ATOMIC_RELAXED, __HIP_MEMORY_SCOPE_AGENT)
           < (unsigned)GRID)
      __builtin_amdgcn_s_sleep(2);
  }
  __syncthreads();
  __threadfence();            // acquire remote partials

  // ---------------- phase 2: 64 points, 4 lanes each (R11 body) -----------
  constexpr int H = NC / 2;   // lists per lane
  const int g = slice * 256 + tid;
  const int p = g >> 2;                  // point id 0 .. 16383
  const int r = g & 3;                   // 0: pred/h0, 1: pred/h1, 2: tgt/h0, 3: tgt/h1
  const int cl = r >> 1;
  const int hf = r & 1;
  const int b = p >> 12;
  const int i = p & (NPTS - 1);

  const float* __restrict__ C = (cl ? tgt : pred) + (size_t)b * NPTS * 3;
  const size_t stride = (size_t)NPTS * KNN;

  // batched load of this lane's H=4 lists (8 independent uint4 loads -> MLP),
  // tree-merge, then xor1 combine across halves.
  uint32_t v[KNN];
  {
    const uint32_t* base = partial +
        ((size_t)(cl * BATCH + b) * NC + (size_t)hf * H) * stride + (size_t)i * KNN;
    uint32_t L[H][KNN];
#pragma unroll
    for (int c = 0; c < H; ++c) {
      const uint4 a0 = *(const uint4*)(base + (size_t)c * stride);
      const uint4 a1 = *(const uint4*)(base + (size_t)c * stride + 4);
      L[c][0] = a0.x; L[c][1] = a0.y; L[c][2] = a0.z; L[c][3] = a0.w;
      L[c][4] = a1.x; L[c][5] = a1.y; L[c][6] = a1.z; L[c][7] = a1.w;
    }
    merge2(L[0], L[1]); merge2(L[2], L[3]);
    merge2(L[0], L[2]);
#pragma unroll
    for (int m = 0; m < KNN; ++m) v[m] = L[0][m];
    uint32_t o[KNN];
#pragma unroll
    for (int m = 0; m < KNN; ++m) o[m] = __shfl_xor(v[m], 1);
    merge2(v, o);  // both half-lanes now hold the cloud's final sorted top-8
  }

  // coord pass: this lane's k-half (4 neighbors)
  const float qx = C[3 * i], qy = C[3 * i + 1], qz = C[3 * i + 2];
  float nx[4], ny[4], nz[4];
  float dsum = 0.f, cov[6] = {0, 0, 0, 0, 0, 0};
#pragma unroll
  for (int kk = 0; kk < 4; ++kk) {
    const int j = (int)(v[hf * 4 + kk] & 0xFFFu);
    const float ax = C[3 * j] - qx, ay = C[3 * j + 1] - qy, az = C[3 * j + 2] - qz;
    const float d2 = fmaf(ax, ax, fmaf(ay, ay, az * az));
    const float dist = sqrtf(fmaxf(d2, EPS_F));
    const float inv = 1.0f / fmaxf(dist, EPS_F);
    dsum += dist;
    cov[0] += ax * ax; cov[1] += ay * ay; cov[2] += az * az;
    cov[3] += ax * ay; cov[4] += ax * az; cov[5] += ay * az;
    nx[kk] = ax * inv; ny[kk] = ay * inv; nz[kk] = az * inv;
  }

  // direction: partner xor2 = other cloud, same k-half
  float spart = 0.f;
#pragma unroll
  for (int kk = 0; kk < 4; ++kk) {
    const float ox = __shfl_xor(nx[kk], 2);
    const float oy = __shfl_xor(ny[kk], 2);
    const float oz = __shfl_xor(nz[kk], 2);
    spart += nx[kk] * ox + ny[kk] * oy + nz[kk] * oz;
  }
  float s = (r < 2) ? spart : 0.f;  // pred lanes cover k 0-3 / 4-7 once

  // cloud totals (xor1), cross-cloud exchange (xor2)
  dsum += __shfl_xor(dsum, 1);
#pragma unroll
  for (int m = 0; m < 6; ++m) cov[m] += __shfl_xor(cov[m], 1);
  const float dsum_o = __shfl_xor(dsum, 2);
  float cov_o[6];
#pragma unroll
  for (int m = 0; m < 6; ++m) cov_o[m] = __shfl_xor(cov[m], 2);

  float e = 0.f, cfro = 0.f;
  if (r == 0) {
    const float densp = dsum * (1.0f / KNN);
    const float denst = dsum_o * (1.0f / KNN);
    e = (densp - denst) * (densp - denst);
    const float dxx = (cov[0] - cov_o[0]) * (1.0f / KNN);
    const float dyy = (cov[1] - cov_o[1]) * (1.0f / KNN);
    const float dzz = (cov[2] - cov_o[2]) * (1.0f / KNN);
    const float dxy = (cov[3] - cov_o[3]) * (1.0f / KNN);
    const float dxz = (cov[4] - cov_o[4]) * (1.0f / KNN);
    const float dyz = (cov[5] - cov_o[5]) * (1.0f / KNN);
    cfro = sqrtf(dxx * dxx + dyy * dyy + dzz * dzz
                 + 2.0f * (dxy * dxy + dxz * dxz + dyz * dyz));
  }

  // block reduce (4 waves) + atomic + finalize ticket
#pragma unroll
  for (int off = 32; off > 0; off >>= 1) {
    e    += __shfl_down(e, off);
    s    += __shfl_down(s, off);
    cfro += __shfl_down(cfro, off);
  }
  const int wv = tid >> 6;
  if ((tid & 63) == 0) { red[wv] = e; red[4 + wv] = s; red[8 + wv] = cfro; }
  __syncthreads();
  if (tid == 0) {
    atomicAdd(&acc[0], (double)(red[0] + red[1] + red[2] + red[3]));
    atomicAdd(&acc[1], (double)(red[4] + red[5] + red[6] + red[7]));
    atomicAdd(&acc[2], (double)(red[8] + red[9] + red[10] + red[11]));
    __threadfence();
    const unsigned fin = atomicAdd(&counters[1], 1u) + 1u;
    if (fin == (unsigned)NMERGE) {
      __threadfence();
      const double ee = __hip_atomic_load(&acc[0], __ATOMIC_RELAXED, __HIP_MEMORY_SCOPE_AGENT);
      const double ss = __hip_atomic_load(&acc[1], __ATOMIC_RELAXED, __HIP_MEMORY_SCOPE_AGENT);
      const double cc = __hip_atomic_load(&acc[2], __ATOMIC_RELAXED, __HIP_MEMORY_SCOPE_AGENT);
      const double BN = (double)BATCH * (double)NPTS;
      out[0] = (float)(ee / BN + 0.5 * (1.0 - ss / (BN * (double)KNN)) + 0.5 * (cc / BN));
    }
  }
}

extern "C" void kernel_launch(void* const* d_in, const int* in_sizes, int n_in,
                              void* d_out, int out_size, void* d_ws, size_t ws_size,
                              hipStream_t stream) {
  const float* pred = (const float*)d_in[0];
  const float* tgt  = (const float*)d_in[1];
  uint32_t* counters = (uint32_t*)d_ws;                 // 2 u32 @ 0
  double* acc = (double*)((char*)d_ws + 16);            // 3 doubles @ 16
  uint32_t* partial = (uint32_t*)((char*)d_ws + 4096);  // 8.4 MB (NC=8)

  hipMemsetAsync(d_ws, 0, 64, stream);
  fused_k<<<GRID, 256, 0, stream>>>(pred, tgt, partial, acc, counters,
                                    (float*)d_out);
}

// Round 13
// 106.138 us; speedup vs baseline: 2.2849x; 2.2849x over previous
//
#include <hip/hip_runtime.h>
#include <cstdint>
#include <cstddef>

#define NPTS   4096
#define BATCH  4
#define KNN    8
#define NC     16          // chunks per cloud scan
#define CHN    (NPTS / NC) // 256 candidates per chunk
#define PD     4           // partial list depth per chunk (top-4; see proof above)
#define EPS_F  1e-12f

__device__ __forceinline__ uint32_t u32min(uint32_t a, uint32_t b) { return a < b ? a : b; }
__device__ __forceinline__ uint32_t u32max(uint32_t a, uint32_t b) { return a > b ? a : b; }

// v_med3_u32: for sorted a<=b, med3(a,b,x) == clamp(x,a,b) — one instruction.
__device__ __forceinline__ uint32_t umed3(uint32_t a, uint32_t b, uint32_t c) {
  uint32_t d;
  asm("v_med3_u32 %0, %1, %2, %3" : "=v"(d) : "v"(a), "v"(b), "v"(c));
  return d;
}

// Insert key into ascending D-list, dropping the largest: 1 min + (D-1) med3.
template <int D>
__device__ __forceinline__ void insertD(uint32_t (&loc)[D], uint32_t key) {
  uint32_t prev = loc[0];
  loc[0] = u32min(prev, key);
#pragma unroll
  for (int m = 1; m < D; ++m) {
    const uint32_t cur = loc[m];
    loc[m] = umed3(prev, cur, key);
    prev = cur;
  }
}

// Proven float4 candidate-stream scan (R4 structure), depth-parametric.
template <int D>
__device__ __forceinline__ void scan_chunk(const float4* __restrict__ c4, int j0,
                                           float xix, float xiy, float xiz,
                                           uint32_t (&loc)[D]) {
#pragma unroll
  for (int k = 0; k < D; ++k) loc[k] = 0xFFFFFFFFu;
#pragma unroll 4
  for (int t4 = 0; t4 < CHN / 4; ++t4) {
    const float4 q0 = c4[3 * t4 + 0];  // x0 y0 z0 x1
    const float4 q1 = c4[3 * t4 + 1];  // y1 z1 x2 y2
    const float4 q2 = c4[3 * t4 + 2];  // z2 x3 y3 z3
    const uint32_t jb = (uint32_t)(j0 + 4 * t4);
    {
      const float dx = xix - q0.x, dy = xiy - q0.y, dz = xiz - q0.z;
      const float d2 = fmaf(dx, dx, fmaf(dy, dy, dz * dz));
      insertD<D>(loc, (__float_as_uint(d2) & 0xFFFFF000u) | (jb + 0u));
    }
    {
      const float dx = xix - q0.w, dy = xiy - q1.x, dz = xiz - q1.y;
      const float d2 = fmaf(dx, dx, fmaf(dy, dy, dz * dz));
      insertD<D>(loc, (__float_as_uint(d2) & 0xFFFFF000u) | (jb + 1u));
    }
    {
      const float dx = xix - q1.z, dy = xiy - q1.w, dz = xiz - q2.x;
      const float d2 = fmaf(dx, dx, fmaf(dy, dy, dz * dz));
      insertD<D>(loc, (__float_as_uint(d2) & 0xFFFFF000u) | (jb + 2u));
    }
    {
      const float dx = xix - q2.y, dy = xiy - q2.z, dz = xiz - q2.w;
      const float d2 = fmaf(dx, dx, fmaf(dy, dy, dz * dz));
      insertD<D>(loc, (__float_as_uint(d2) & 0xFFFFF000u) | (jb + 3u));
    }
  }
}

// ---------------------------------------------------------------------------
// Kernel 1: per-(cloud,batch,point,chunk) top-4 by truncated key (top-5 with
// self-drop for the self chunk — block-uniform branch). Key =
// (float_bits(d2) & 0xFFFFF000) | j; ties -> ascending j (lax.top_k).
// NC=16 -> 2048 blocks; proven float4 VMEM stream, unroll 4, bounds(256,4).
// Block 0 zeroes acc/ticket (kernel-boundary ordering covers loss_k).
// ---------------------------------------------------------------------------
__global__ void __launch_bounds__(256, 4)
knn_partial_k(const float* __restrict__ pred, const float* __restrict__ tgt,
              uint32_t* __restrict__ partial, double* __restrict__ acc,
              uint32_t* __restrict__ ticket) {
  if (blockIdx.x == 0 && threadIdx.x == 0) {
    acc[0] = 0.0; acc[1] = 0.0; acc[2] = 0.0;
    *ticket = 0u;
  }

  int bx = blockIdx.x;
  const int chunk = bx & (NC - 1); bx /= NC;
  const int ig    = bx & 15; bx >>= 4;
  const int b     = bx & 3;  bx >>= 2;
  const int cloud = bx;  // 0 = pred, 1 = target

  const float* __restrict__ pts = (cloud ? tgt : pred) + (size_t)b * NPTS * 3;
  const int tid = threadIdx.x;
  const int i = ig * 256 + tid;
  const int j0 = chunk * CHN;

  const float xix = pts[3 * i + 0];
  const float xiy = pts[3 * i + 1];
  const float xiz = pts[3 * i + 2];

  const float4* __restrict__ c4 = (const float4*)(pts + 3 * j0);

  uint4 o;
  if (ig == chunk) {           // self chunk (CHN == 256): depth 5, drop rank 0
    uint32_t loc[PD + 1];
    scan_chunk<PD + 1>(c4, j0, xix, xiy, xiz, loc);
    o = make_uint4(loc[1], loc[2], loc[3], loc[4]);
  } else {
    uint32_t loc[PD];
    scan_chunk<PD>(c4, j0, xix, xiy, xiz, loc);
    o = make_uint4(loc[0], loc[1], loc[2], loc[3]);
  }
  uint32_t* p = partial +
      ((((size_t)(cloud * BATCH + b) * NC + chunk) * NPTS) + (size_t)i) * PD;
  *(uint4*)p = o;
}

// Merge two sorted-ascending 8-lists, keep the smallest 8, sorted (20 CE-ish).
__device__ __forceinline__ void merge2(uint32_t A[KNN], const uint32_t B[KNN]) {
  uint32_t t[KNN];
#pragma unroll
  for (int m = 0; m < KNN; ++m) t[m] = u32min(A[m], B[KNN - 1 - m]);
#define CEU(x, y) { uint32_t lo = u32min(t[x], t[y]); uint32_t hi = u32max(t[x], t[y]); t[x] = lo; t[y] = hi; }
  CEU(0,4) CEU(1,5) CEU(2,6) CEU(3,7)
  CEU(0,2) CEU(1,3) CEU(4,6) CEU(5,7)
  CEU(0,1) CEU(2,3) CEU(4,5) CEU(6,7)
#undef CEU
#pragma unroll
  for (int m = 0; m < KNN; ++m) A[m] = t[m];
}

// Two sorted-4 lists -> one fully sorted 8 (bitonic cleanup, 12 CEs).
__device__ __forceinline__ void merge44(const uint2 a0, const uint2 a1,
                                        const uint2 b0, const uint2 b1,
                                        uint32_t s[KNN]) {
  s[0] = a0.x; s[1] = a0.y; s[2] = a1.x; s[3] = a1.y;
  s[4] = b1.y; s[5] = b1.x; s[6] = b0.y; s[7] = b0.x;  // b reversed -> bitonic
#define CEU(x, y) { uint32_t lo = u32min(s[x], s[y]); uint32_t hi = u32max(s[x], s[y]); s[x] = lo; s[y] = hi; }
  CEU(0,4) CEU(1,5) CEU(2,6) CEU(3,7)
  CEU(0,2) CEU(1,3) CEU(4,6) CEU(5,7)
  CEU(0,1) CEU(2,3) CEU(4,5) CEU(6,7)
#undef CEU
}

// Merge all NC=16 sorted-4 lists for point i -> global top-8 (sorted).
__device__ __forceinline__ void merge_all(const uint32_t* __restrict__ base,
                                          int i, uint32_t v[KNN]) {
  const size_t stride = (size_t)NPTS * PD;
  const uint32_t* p = base + (size_t)i * PD;
  // batched loads: 32 independent uint2s -> MLP
  uint2 q[NC][2];
#pragma unroll
  for (int c = 0; c < NC; ++c) {
    q[c][0] = *(const uint2*)(p + (size_t)c * stride);
    q[c][1] = *(const uint2*)(p + (size_t)c * stride + 2);
  }
  uint32_t L[NC / 2][KNN];
#pragma unroll
  for (int c = 0; c < NC / 2; ++c)
    merge44(q[2 * c][0], q[2 * c][1], q[2 * c + 1][0], q[2 * c + 1][1], L[c]);
  merge2(L[0], L[1]); merge2(L[2], L[3]); merge2(L[4], L[5]); merge2(L[6], L[7]);
  merge2(L[0], L[2]); merge2(L[4], L[6]);
  merge2(L[0], L[4]);
#pragma unroll
  for (int m = 0; m < KNN; ++m) v[m] = L[0][m];
}

// Per-cloud: coord gather (8 independent loads), density/cov/unit vectors.
__device__ __forceinline__ void cloud_stats(const float* __restrict__ C, int i,
                                            const uint32_t v[KNN],
                                            float& dsum, float cov[6],
                                            float nx[KNN], float ny[KNN], float nz[KNN]) {
  const float qx = C[3 * i], qy = C[3 * i + 1], qz = C[3 * i + 2];
  float jx[KNN], jy[KNN], jz[KNN];
#pragma unroll
  for (int k = 0; k < KNN; ++k) {
    const int j = (int)(v[k] & 0xFFFu);
    jx[k] = C[3 * j]; jy[k] = C[3 * j + 1]; jz[k] = C[3 * j + 2];
  }
  dsum = 0.f;
#pragma unroll
  for (int m = 0; m < 6; ++m) cov[m] = 0.f;
#pragma unroll
  for (int k = 0; k < KNN; ++k) {
    const float ax = jx[k] - qx, ay = jy[k] - qy, az = jz[k] - qz;
    const float d2 = fmaf(ax, ax, fmaf(ay, ay, az * az));
    const float dist = sqrtf(fmaxf(d2, EPS_F));
    const float inv = 1.0f / fmaxf(dist, EPS_F);
    dsum += dist;
    cov[0] += ax * ax; cov[1] += ay * ay; cov[2] += az * az;
    cov[3] += ax * ay; cov[4] += ax * az; cov[5] += ay * az;
    nx[k] = ax * inv; ny[k] = ay * inv; nz[k] = az * inv;
  }
}

// ---------------------------------------------------------------------------
// Kernel 2: one thread per point, one wave per block, full register file
// ((64,1): grid-limited occupancy, nothing lost). Static indexing only —
// no promote-alloca hazard. Ticket finalize replaces a third kernel.
// ---------------------------------------------------------------------------
__global__ void __launch_bounds__(64, 1)
loss_k(const float* __restrict__ pred, const float* __restrict__ tgt,
       const uint32_t* __restrict__ partial, double* __restrict__ acc,
       uint32_t* __restrict__ ticket, float* __restrict__ out) {
  const int p = blockIdx.x * 64 + threadIdx.x;   // 0 .. 16383
  const int b = p >> 12;
  const int i = p & (NPTS - 1);

  const float* __restrict__ P = pred + (size_t)b * NPTS * 3;
  const float* __restrict__ T = tgt  + (size_t)b * NPTS * 3;

  const size_t cstride = (size_t)NC * NPTS * PD;
  uint32_t vp[KNN], vt[KNN];
  merge_all(partial + (size_t)(0 * BATCH + b) * cstride, i, vp);
  merge_all(partial + (size_t)(1 * BATCH + b) * cstride, i, vt);

  float dsp, dst, pcov[6], tcov[6];
  float pnx[KNN], pny[KNN], pnz[KNN], tnx[KNN], tny[KNN], tnz[KNN];
  cloud_stats(P, i, vp, dsp, pcov, pnx, pny, pnz);
  cloud_stats(T, i, vt, dst, tcov, tnx, tny, tnz);

  float sdot = 0.f;
#pragma unroll
  for (int k = 0; k < KNN; ++k)
    sdot += pnx[k] * tnx[k] + pny[k] * tny[k] + pnz[k] * tnz[k];

  const float densp = dsp * (1.0f / KNN);
  const float denst = dst * (1.0f / KNN);
  float e = (densp - denst) * (densp - denst);

  const float dxx = (pcov[0] - tcov[0]) * (1.0f / KNN);
  const float dyy = (pcov[1] - tcov[1]) * (1.0f / KNN);
  const float dzz = (pcov[2] - tcov[2]) * (1.0f / KNN);
  const float dxy = (pcov[3] - tcov[3]) * (1.0f / KNN);
  const float dxz = (pcov[4] - tcov[4]) * (1.0f / KNN);
  const float dyz = (pcov[5] - tcov[5]) * (1.0f / KNN);
  float cfro = sqrtf(dxx * dxx + dyy * dyy + dzz * dzz
                     + 2.0f * (dxy * dxy + dxz * dxz + dyz * dyz));
  float s = sdot;

#pragma unroll
  for (int off = 32; off > 0; off >>= 1) {
    e    += __shfl_down(e, off);
    s    += __shfl_down(s, off);
    cfro += __shfl_down(cfro, off);
  }
  if (threadIdx.x == 0) {
    atomicAdd(&acc[0], (double)e);
    atomicAdd(&acc[1], (double)s);
    atomicAdd(&acc[2], (double)cfro);
    __threadfence();
    const unsigned rank = atomicAdd(ticket, 1u) + 1u;
    if (rank == (unsigned)((BATCH * NPTS) / 64)) {
      __threadfence();
      const double ee = __hip_atomic_load(&acc[0], __ATOMIC_RELAXED, __HIP_MEMORY_SCOPE_AGENT);
      const double ss = __hip_atomic_load(&acc[1], __ATOMIC_RELAXED, __HIP_MEMORY_SCOPE_AGENT);
      const double cc = __hip_atomic_load(&acc[2], __ATOMIC_RELAXED, __HIP_MEMORY_SCOPE_AGENT);
      const double BN = (double)BATCH * (double)NPTS;
      out[0] = (float)(ee / BN + 0.5 * (1.0 - ss / (BN * (double)KNN)) + 0.5 * (cc / BN));
    }
  }
}

extern "C" void kernel_launch(void* const* d_in, const int* in_sizes, int n_in,
                              void* d_out, int out_size, void* d_ws, size_t ws_size,
                              hipStream_t stream) {
  const float* pred = (const float*)d_in[0];
  const float* tgt  = (const float*)d_in[1];
  double* acc = (double*)d_ws;                       // 3 doubles @ 0
  uint32_t* ticket = (uint32_t*)((char*)d_ws + 64);  // 1 u32 @ 64
  uint32_t* partial = (uint32_t*)((char*)d_ws + 4096);  // 8.4 MB

  knn_partial_k<<<2 * BATCH * (NPTS / 256) * NC, 256, 0, stream>>>(
      pred, tgt, partial, acc, ticket);
  loss_k<<<(BATCH * NPTS) / 64, 64, 0, stream>>>(
      pred, tgt, partial, acc, ticket, (float*)d_out);
}